// Round 7
// baseline (749.546 us; speedup 1.0000x reference)
//
#include <hip/hip_runtime.h>
#include <hip/hip_bf16.h>
#include <math.h>

#define Bn 1024
#define Sn 100
#define Hn 1024
#define An 128
#define NHEADS 4
#define Jn 512  // An*NHEADS

// ---------------------------------------------------------------- K0: PE table + column sums
__global__ __launch_bounds__(256) void k0_pe(float* __restrict__ pe, float* __restrict__ pesum) {
    int h = blockIdx.x * 256 + threadIdx.x;
    if (h >= Hn) return;
    int i = h >> 1;
    const float c = (float)(-9.210340371976184 / (double)Hn);  // -ln(10000)/H
    float divv = expf((float)(2 * i) * c);
    float sum = 0.f;
    for (int s = 0; s < Sn; ++s) {
        float arg = (float)s * divv;
        float val = (h & 1) ? cosf(arg) : sinf(arg);
        pe[(size_t)s * Hn + h] = val;
        sum += val;
    }
    pesum[h] = sum;
}

// ---------------------------------------------------------------- K1: xsum[b,h] = sum_s x[b,s,h] + pesum[h]
__global__ __launch_bounds__(256) void k1_xsum(const float* __restrict__ x,
                                               const float* __restrict__ pesum,
                                               float* __restrict__ xsum) {
    int b = blockIdx.x;
    int t = threadIdx.x;
    const float4* xp = (const float4*)(x + (size_t)b * Sn * Hn);
    float4 acc = ((const float4*)pesum)[t];
    #pragma unroll 4
    for (int s = 0; s < Sn; ++s) {
        float4 v = xp[(size_t)s * (Hn / 4) + t];
        acc.x += v.x; acc.y += v.y; acc.z += v.z; acc.w += v.w;
    }
    ((float4*)xsum)[(size_t)b * (Hn / 4) + t] = acc;
}

// ---------------------------------------------------------------- K2: ksum[b,j] = sum_h xsum[b,h] * Wk[j,h]
// C = A @ B^T, A[1024x1024], B[512x1024], both row-major K-contiguous.
// 32(m) x 64(j) tile, K-step 16, transposed LDS for vector fragment reads.
__global__ __launch_bounds__(256) void k2_gemm_abt(const float* __restrict__ Amat,
                                                   const float* __restrict__ Bmat,
                                                   float* __restrict__ Cmat) {
    __shared__ float As[16][36];  // [k][m], pad 36
    __shared__ float Bs[16][68];  // [k][j], pad 68
    int tid = threadIdx.x;
    int m0 = blockIdx.x * 32, j0 = blockIdx.y * 64;
    int tx = tid & 15, ty = tid >> 4;  // tx: j/4 (0..15), ty: m/2 (0..15)
    float acc[2][4] = {};
    int bj = tid >> 2, bk = (tid & 3) * 4;       // B loader: row j (0..63), k col
    int am = tid >> 2, ak = (tid & 3) * 4;       // A loader (tid<128): row m (0..31), k col
    for (int kb = 0; kb < Hn; kb += 16) {
        float4 bv = *(const float4*)(Bmat + (size_t)(j0 + bj) * Hn + kb + bk);
        Bs[bk + 0][bj] = bv.x; Bs[bk + 1][bj] = bv.y; Bs[bk + 2][bj] = bv.z; Bs[bk + 3][bj] = bv.w;
        if (tid < 128) {
            float4 av = *(const float4*)(Amat + (size_t)(m0 + am) * Hn + kb + ak);
            As[ak + 0][am] = av.x; As[ak + 1][am] = av.y; As[ak + 2][am] = av.z; As[ak + 3][am] = av.w;
        }
        __syncthreads();
        #pragma unroll
        for (int kk = 0; kk < 16; ++kk) {
            float2 a = *(const float2*)&As[kk][ty * 2];
            float4 b = *(const float4*)&Bs[kk][tx * 4];
            acc[0][0] = fmaf(a.x, b.x, acc[0][0]);
            acc[0][1] = fmaf(a.x, b.y, acc[0][1]);
            acc[0][2] = fmaf(a.x, b.z, acc[0][2]);
            acc[0][3] = fmaf(a.x, b.w, acc[0][3]);
            acc[1][0] = fmaf(a.y, b.x, acc[1][0]);
            acc[1][1] = fmaf(a.y, b.y, acc[1][1]);
            acc[1][2] = fmaf(a.y, b.z, acc[1][2]);
            acc[1][3] = fmaf(a.y, b.w, acc[1][3]);
        }
        __syncthreads();
    }
    #pragma unroll
    for (int r = 0; r < 2; ++r) {
        float4 o = make_float4(acc[r][0], acc[r][1], acc[r][2], acc[r][3]);
        *(float4*)(Cmat + (size_t)(m0 + ty * 2 + r) * Jn + j0 + tx * 4) = o;
    }
}

// ---------------------------------------------------------------- K3: v[b,n,h] = sum_a ksum[b, n*128+a] * Wq[n*128+a, h]
// per-n GEMM: A[1024x128] (stride 512) @ B[128x1024] (stride 1024)
__global__ __launch_bounds__(256) void k3_gemm_ab(const float* __restrict__ ksum,
                                                  const float* __restrict__ Wq,
                                                  float* __restrict__ v) {
    __shared__ float As[64][17];
    __shared__ float Bs[16][64];
    int tid = threadIdx.x;
    int m0 = blockIdx.x * 64, j0 = blockIdx.y * 64, n = blockIdx.z;
    int tx = tid & 15, ty = tid >> 4;
    float acc[4][4] = {};
    int li = tid * 4;
    int ar = li >> 4, ac = li & 15;   // A tile 64x16
    int br = li >> 6, bc = li & 63;   // B tile 16x64
    for (int kb = 0; kb < An; kb += 16) {
        float4 av = *(const float4*)(ksum + (size_t)(m0 + ar) * Jn + n * An + kb + ac);
        As[ar][ac + 0] = av.x; As[ar][ac + 1] = av.y; As[ar][ac + 2] = av.z; As[ar][ac + 3] = av.w;
        float4 bv = *(const float4*)(Wq + (size_t)(n * An + kb + br) * Hn + j0 + bc);
        Bs[br][bc + 0] = bv.x; Bs[br][bc + 1] = bv.y; Bs[br][bc + 2] = bv.z; Bs[br][bc + 3] = bv.w;
        __syncthreads();
        #pragma unroll
        for (int kk = 0; kk < 16; ++kk) {
            float a[4], b[4];
            #pragma unroll
            for (int r = 0; r < 4; ++r) a[r] = As[ty * 4 + r][kk];
            #pragma unroll
            for (int cidx = 0; cidx < 4; ++cidx) b[cidx] = Bs[kk][tx * 4 + cidx];
            #pragma unroll
            for (int r = 0; r < 4; ++r)
                #pragma unroll
                for (int cidx = 0; cidx < 4; ++cidx)
                    acc[r][cidx] = fmaf(a[r], b[cidx], acc[r][cidx]);
        }
        __syncthreads();
    }
    // v layout [b][n][h]
    #pragma unroll
    for (int r = 0; r < 4; ++r) {
        int b = m0 + ty * 4 + r;
        #pragma unroll
        for (int cidx = 0; cidx < 4; ++cidx) {
            int h = j0 + tx * 4 + cidx;
            v[((size_t)b * NHEADS + n) * Hn + h] = acc[r][cidx];
        }
    }
}

// ---------------------------------------------------------------- K4: logits + gumbel argmax + gather
__global__ __launch_bounds__(256) void k4_final(const float* __restrict__ x,
                                                const float* __restrict__ pe,
                                                const float* __restrict__ v,
                                                const float* __restrict__ gu,
                                                float* __restrict__ out) {
    int b = blockIdx.x;
    int tid = threadIdx.x;
    int wave = tid >> 6, lane = tid & 63;
    __shared__ float vL[NHEADS][Hn];  // 16 KB
    __shared__ float redVal[4][NHEADS];
    __shared__ int redS[4][NHEADS];
    __shared__ int sstar[NHEADS];

    const float4* vg = (const float4*)(v + (size_t)b * NHEADS * Hn);
    float4* vls = (float4*)&vL[0][0];
    for (int i = tid; i < NHEADS * Hn / 4; i += 256) vls[i] = vg[i];
    __syncthreads();

    float bestVal[NHEADS] = {-1e30f, -1e30f, -1e30f, -1e30f};
    int bestS[NHEADS] = {0, 0, 0, 0};
    const float scale = 1.0f / 3200.0f;  // 1/(sqrt(1024)*100)

    for (int s = wave; s < Sn; s += 4) {
        const float4* xr = (const float4*)(x + ((size_t)b * Sn + s) * Hn);
        const float4* pr = (const float4*)(pe + (size_t)s * Hn);
        float acc0 = 0.f, acc1 = 0.f, acc2 = 0.f, acc3 = 0.f;
        #pragma unroll
        for (int k = 0; k < 4; ++k) {
            int idx = k * 64 + lane;
            float4 xv = xr[idx];
            float4 pv = pr[idx];
            float t0 = xv.x + pv.x, t1 = xv.y + pv.y, t2 = xv.z + pv.z, t3 = xv.w + pv.w;
            float4 v0 = ((const float4*)&vL[0][0])[idx];
            float4 v1 = ((const float4*)&vL[1][0])[idx];
            float4 v2 = ((const float4*)&vL[2][0])[idx];
            float4 v3 = ((const float4*)&vL[3][0])[idx];
            acc0 += t0 * v0.x + t1 * v0.y + t2 * v0.z + t3 * v0.w;
            acc1 += t0 * v1.x + t1 * v1.y + t2 * v1.z + t3 * v1.w;
            acc2 += t0 * v2.x + t1 * v2.y + t2 * v2.z + t3 * v2.w;
            acc3 += t0 * v3.x + t1 * v3.y + t2 * v3.z + t3 * v3.w;
        }
        float accs[4] = {acc0, acc1, acc2, acc3};
        #pragma unroll
        for (int n = 0; n < NHEADS; ++n) {
            float a = accs[n];
            #pragma unroll
            for (int off = 32; off > 0; off >>= 1) a += __shfl_xor(a, off, 64);
            float u = gu[((size_t)b * NHEADS + n) * Sn + s];
            float g = -logf(-logf(u + 1e-10f) + 1e-10f);
            float tot = a * scale + g;
            if (tot > bestVal[n]) { bestVal[n] = tot; bestS[n] = s; }
        }
    }
    if (lane == 0) {
        #pragma unroll
        for (int n = 0; n < NHEADS; ++n) {
            redVal[wave][n] = bestVal[n];
            redS[wave][n] = bestS[n];
        }
    }
    __syncthreads();
    if (tid < NHEADS) {
        float bv = redVal[0][tid];
        int bs = redS[0][tid];
        for (int w = 1; w < 4; ++w) {
            float vv = redVal[w][tid];
            int ss = redS[w][tid];
            if (vv > bv || (vv == bv && ss < bs)) { bv = vv; bs = ss; }
        }
        sstar[tid] = bs;
    }
    __syncthreads();
    // gather: out[b,n,:] = x[b, sstar[n], :]
    #pragma unroll
    for (int n = 0; n < NHEADS; ++n) {
        const float4* src = (const float4*)(x + ((size_t)b * Sn + sstar[n]) * Hn);
        float4* dst = (float4*)(out + ((size_t)b * NHEADS + n) * Hn);
        dst[tid] = src[tid];
    }
}

// ----------------------------------------------------------------
extern "C" void kernel_launch(void* const* d_in, const int* in_sizes, int n_in,
                              void* d_out, int out_size, void* d_ws, size_t ws_size,
                              hipStream_t stream) {
    const float* x  = (const float*)d_in[0];
    const float* Wq = (const float*)d_in[1];
    const float* Wk = (const float*)d_in[2];
    const float* gu = (const float*)d_in[3];
    float* out = (float*)d_out;
    float* ws = (float*)d_ws;

    float* pe    = ws;                     // S*H  = 102400
    float* pesum = pe + (size_t)Sn * Hn;   // H    = 1024
    float* xsum  = pesum + Hn;             // B*H  = 1048576
    float* ksum  = xsum + (size_t)Bn * Hn; // B*J  = 524288
    float* v     = out;                    // B*N*H — reuse d_out as scratch for v

    k0_pe<<<dim3(Hn / 256), dim3(256), 0, stream>>>(pe, pesum);
    k1_xsum<<<dim3(Bn), dim3(256), 0, stream>>>(x, pesum, xsum);
    k2_gemm_abt<<<dim3(Bn / 32, Jn / 64), dim3(256), 0, stream>>>(xsum, Wk, ksum);
    k3_gemm_ab<<<dim3(Bn / 64, Hn / 64, NHEADS), dim3(256), 0, stream>>>(ksum, Wq, v);
    k4_final<<<dim3(Bn), dim3(256), 0, stream>>>(x, pe, v, gu, out);
}

// Round 9
// 710.008 us; speedup vs baseline: 1.0557x; 1.0557x over previous
//
#include <hip/hip_runtime.h>
#include <hip/hip_bf16.h>
#include <math.h>

#define Bn 1024
#define Sn 100
#define Hn 1024
#define An 128
#define NHEADS 4
#define Jn 512  // An*NHEADS
#define KSPLIT 8

// ---------------------------------------------------------------- K0a: PE table (one block per s)
__global__ __launch_bounds__(256) void k0a_pe(float* __restrict__ pe) {
    int s = blockIdx.x;
    int t = threadIdx.x;
    int h0 = t * 4;
    const float c = (float)(-9.210340371976184 / (double)Hn);  // -ln(10000)/H
    float d0 = expf((float)h0 * c);          // div for i = h0/2   (2*i = h0)
    float d1 = expf((float)(h0 + 2) * c);    // div for i = h0/2+1
    float a0 = (float)s * d0, a1 = (float)s * d1;
    float4 o;
    o.x = sinf(a0); o.y = cosf(a0); o.z = sinf(a1); o.w = cosf(a1);
    ((float4*)(pe + (size_t)s * Hn))[t] = o;
}

// ---------------------------------------------------------------- K0b: pesum[h] = sum_s pe[s][h]
__global__ __launch_bounds__(256) void k0b_pesum(const float* __restrict__ pe,
                                                 float* __restrict__ pesum) {
    int h = blockIdx.x * 256 + threadIdx.x;
    float s = 0.f;
    for (int i = 0; i < Sn; ++i) s += pe[(size_t)i * Hn + h];
    pesum[h] = s;
}

// ---------------------------------------------------------------- K1: xsum[b,h] = sum_s x[b,s,h] + pesum[h]
__global__ __launch_bounds__(256) void k1_xsum(const float* __restrict__ x,
                                               const float* __restrict__ pesum,
                                               float* __restrict__ xsum) {
    int b = blockIdx.x;
    int t = threadIdx.x;
    const float4* xp = (const float4*)(x + (size_t)b * Sn * Hn);
    float4 acc = ((const float4*)pesum)[t];
    #pragma unroll 4
    for (int s = 0; s < Sn; ++s) {
        float4 v = xp[(size_t)s * (Hn / 4) + t];
        acc.x += v.x; acc.y += v.y; acc.z += v.z; acc.w += v.w;
    }
    ((float4*)xsum)[(size_t)b * (Hn / 4) + t] = acc;
}

// ---------------------------------------------------------------- K2p: partial ksum, C[m,j] = sum_k A[m,k]*B[j,k]
// A=xsum[1024][1024], B=Wk[512][1024]. 128x128 C-tile, 8x8/thread, K-split 8.
__global__ __launch_bounds__(256) void k2p_gemm(const float* __restrict__ Amat,
                                                const float* __restrict__ Bmat,
                                                float* __restrict__ kpart) {
    __shared__ float Ast[16][132];  // [k][m]
    __shared__ float Bst[16][132];  // [k][j]
    int tid = threadIdx.x;
    int m0 = blockIdx.x * 128, j0 = blockIdx.y * 128;
    int kc = blockIdx.z * 128;
    int tx = tid & 15, ty = tid >> 4;
    int lr = tid >> 1, lc = (tid & 1) * 8;
    float acc[8][8] = {};
    for (int kb = 0; kb < 128; kb += 16) {
        const float* ap = Amat + (size_t)(m0 + lr) * Hn + kc + kb + lc;
        float4 a0v = *(const float4*)(ap), a1v = *(const float4*)(ap + 4);
        Ast[lc + 0][lr] = a0v.x; Ast[lc + 1][lr] = a0v.y; Ast[lc + 2][lr] = a0v.z; Ast[lc + 3][lr] = a0v.w;
        Ast[lc + 4][lr] = a1v.x; Ast[lc + 5][lr] = a1v.y; Ast[lc + 6][lr] = a1v.z; Ast[lc + 7][lr] = a1v.w;
        const float* bp = Bmat + (size_t)(j0 + lr) * Hn + kc + kb + lc;
        float4 b0v = *(const float4*)(bp), b1v = *(const float4*)(bp + 4);
        Bst[lc + 0][lr] = b0v.x; Bst[lc + 1][lr] = b0v.y; Bst[lc + 2][lr] = b0v.z; Bst[lc + 3][lr] = b0v.w;
        Bst[lc + 4][lr] = b1v.x; Bst[lc + 5][lr] = b1v.y; Bst[lc + 6][lr] = b1v.z; Bst[lc + 7][lr] = b1v.w;
        __syncthreads();
        #pragma unroll
        for (int kk = 0; kk < 16; ++kk) {
            float4 af0 = *(const float4*)&Ast[kk][ty * 8];
            float4 af1 = *(const float4*)&Ast[kk][ty * 8 + 4];
            float4 bf0 = *(const float4*)&Bst[kk][tx * 8];
            float4 bf1 = *(const float4*)&Bst[kk][tx * 8 + 4];
            float am[8] = {af0.x, af0.y, af0.z, af0.w, af1.x, af1.y, af1.z, af1.w};
            float bn[8] = {bf0.x, bf0.y, bf0.z, bf0.w, bf1.x, bf1.y, bf1.z, bf1.w};
            #pragma unroll
            for (int r = 0; r < 8; ++r)
                #pragma unroll
                for (int cc = 0; cc < 8; ++cc)
                    acc[r][cc] = fmaf(am[r], bn[cc], acc[r][cc]);
        }
        __syncthreads();
    }
    float* outp = kpart + (size_t)blockIdx.z * Bn * Jn;
    #pragma unroll
    for (int r = 0; r < 8; ++r) {
        float4 o0 = make_float4(acc[r][0], acc[r][1], acc[r][2], acc[r][3]);
        float4 o1 = make_float4(acc[r][4], acc[r][5], acc[r][6], acc[r][7]);
        float* row = outp + (size_t)(m0 + ty * 8 + r) * Jn + j0 + tx * 8;
        *(float4*)(row) = o0;
        *(float4*)(row + 4) = o1;
    }
}

// ---------------------------------------------------------------- K2r: ksum = sum over splits (ascending, deterministic)
__global__ __launch_bounds__(256) void k2r_reduce(const float* __restrict__ kpart,
                                                  float* __restrict__ ksum) {
    int i = blockIdx.x * 256 + threadIdx.x;  // float4 index; total Bn*Jn/4 = 131072
    float4 s = ((const float4*)kpart)[i];
    #pragma unroll
    for (int sp = 1; sp < KSPLIT; ++sp) {
        float4 p = ((const float4*)(kpart + (size_t)sp * Bn * Jn))[i];
        s.x += p.x; s.y += p.y; s.z += p.z; s.w += p.w;
    }
    ((float4*)ksum)[i] = s;
}

// ---------------------------------------------------------------- K3p: v[b,n,h] = sum_a ksum[b,n*128+a]*Wq[n*128+a,h]
// 128(b) x 128(h) tile per block, 8x8/thread, K=128 (no split). grid (8, 8, 4)
__global__ __launch_bounds__(256) void k3p_gemm(const float* __restrict__ ksum,
                                                const float* __restrict__ Wq,
                                                float* __restrict__ v) {
    __shared__ float Ast[16][132];  // [a][b]
    __shared__ float Bs[16][132];   // [a][h]
    int tid = threadIdx.x;
    int m0 = blockIdx.x * 128, h0 = blockIdx.y * 128, n = blockIdx.z;
    int tx = tid & 15, ty = tid >> 4;
    int lr = tid >> 1, lc = (tid & 1) * 8;
    int brow = tid & 15, bseg = tid >> 4;
    float acc[8][8] = {};
    for (int kb = 0; kb < An; kb += 16) {
        const float* ap = ksum + (size_t)(m0 + lr) * Jn + n * An + kb + lc;
        float4 a0v = *(const float4*)(ap), a1v = *(const float4*)(ap + 4);
        Ast[lc + 0][lr] = a0v.x; Ast[lc + 1][lr] = a0v.y; Ast[lc + 2][lr] = a0v.z; Ast[lc + 3][lr] = a0v.w;
        Ast[lc + 4][lr] = a1v.x; Ast[lc + 5][lr] = a1v.y; Ast[lc + 6][lr] = a1v.z; Ast[lc + 7][lr] = a1v.w;
        const float* bp = Wq + (size_t)(n * An + kb + brow) * Hn + h0 + bseg * 8;
        float4 w0 = *(const float4*)(bp), w1 = *(const float4*)(bp + 4);
        *(float4*)&Bs[brow][bseg * 8] = w0;
        *(float4*)&Bs[brow][bseg * 8 + 4] = w1;
        __syncthreads();
        #pragma unroll
        for (int kk = 0; kk < 16; ++kk) {
            float4 af0 = *(const float4*)&Ast[kk][ty * 8];
            float4 af1 = *(const float4*)&Ast[kk][ty * 8 + 4];
            float4 bf0 = *(const float4*)&Bs[kk][tx * 8];
            float4 bf1 = *(const float4*)&Bs[kk][tx * 8 + 4];
            float am[8] = {af0.x, af0.y, af0.z, af0.w, af1.x, af1.y, af1.z, af1.w};
            float bn[8] = {bf0.x, bf0.y, bf0.z, bf0.w, bf1.x, bf1.y, bf1.z, bf1.w};
            #pragma unroll
            for (int r = 0; r < 8; ++r)
                #pragma unroll
                for (int cc = 0; cc < 8; ++cc)
                    acc[r][cc] = fmaf(am[r], bn[cc], acc[r][cc]);
        }
        __syncthreads();
    }
    #pragma unroll
    for (int r = 0; r < 8; ++r) {
        int b = m0 + ty * 8 + r;
        float* row = v + ((size_t)b * NHEADS + n) * Hn + h0 + tx * 8;
        float4 o0 = make_float4(acc[r][0], acc[r][1], acc[r][2], acc[r][3]);
        float4 o1 = make_float4(acc[r][4], acc[r][5], acc[r][6], acc[r][7]);
        *(float4*)(row) = o0;
        *(float4*)(row + 4) = o1;
    }
}

// ---------------------------------------------------------------- K4: logits + gumbel argmax + gather
__global__ __launch_bounds__(256) void k4_final(const float* __restrict__ x,
                                                const float* __restrict__ pe,
                                                const float* __restrict__ v,
                                                const float* __restrict__ gu,
                                                float* __restrict__ out) {
    int b = blockIdx.x;
    int tid = threadIdx.x;
    int wave = tid >> 6, lane = tid & 63;
    __shared__ float vL[NHEADS][Hn];  // 16 KB
    __shared__ float gL[NHEADS][Sn];  // 1.6 KB gumbel table
    __shared__ float redVal[4][NHEADS];
    __shared__ int redS[4][NHEADS];
    __shared__ int sstar[NHEADS];

    const float4* vg = (const float4*)(v + (size_t)b * NHEADS * Hn);
    float4* vls = (float4*)&vL[0][0];
    for (int i = tid; i < NHEADS * Hn / 4; i += 256) vls[i] = vg[i];
    // gumbel table: gu[(b*N+n)*Sn + s] = gu[b*400 + i], coalesced
    for (int i = tid; i < NHEADS * Sn; i += 256) {
        float u = gu[(size_t)b * (NHEADS * Sn) + i];
        gL[0][i] = -logf(-logf(u + 1e-10f) + 1e-10f);  // flat [n*Sn+s] layout
    }
    __syncthreads();

    float bestVal[NHEADS] = {-1e30f, -1e30f, -1e30f, -1e30f};
    int bestS[NHEADS] = {0, 0, 0, 0};
    const float scale = 1.0f / 3200.0f;  // 1/(sqrt(1024)*100)

    for (int s = wave; s < Sn; s += 4) {
        const float4* xr = (const float4*)(x + ((size_t)b * Sn + s) * Hn);
        const float4* pr = (const float4*)(pe + (size_t)s * Hn);
        float acc0 = 0.f, acc1 = 0.f, acc2 = 0.f, acc3 = 0.f;
        #pragma unroll
        for (int k = 0; k < 4; ++k) {
            int idx = k * 64 + lane;
            float4 xv = xr[idx];
            float4 pv = pr[idx];
            float t0 = xv.x + pv.x, t1 = xv.y + pv.y, t2 = xv.z + pv.z, t3 = xv.w + pv.w;
            float4 v0 = ((const float4*)&vL[0][0])[idx];
            float4 v1 = ((const float4*)&vL[1][0])[idx];
            float4 v2 = ((const float4*)&vL[2][0])[idx];
            float4 v3 = ((const float4*)&vL[3][0])[idx];
            acc0 += t0 * v0.x + t1 * v0.y + t2 * v0.z + t3 * v0.w;
            acc1 += t0 * v1.x + t1 * v1.y + t2 * v1.z + t3 * v1.w;
            acc2 += t0 * v2.x + t1 * v2.y + t2 * v2.z + t3 * v2.w;
            acc3 += t0 * v3.x + t1 * v3.y + t2 * v3.z + t3 * v3.w;
        }
        float accs[4] = {acc0, acc1, acc2, acc3};
        #pragma unroll
        for (int n = 0; n < NHEADS; ++n) {
            float a = accs[n];
            #pragma unroll
            for (int off = 32; off > 0; off >>= 1) a += __shfl_xor(a, off, 64);
            float tot = a * scale + gL[0][n * Sn + s];
            if (tot > bestVal[n]) { bestVal[n] = tot; bestS[n] = s; }
        }
    }
    if (lane == 0) {
        #pragma unroll
        for (int n = 0; n < NHEADS; ++n) {
            redVal[wave][n] = bestVal[n];
            redS[wave][n] = bestS[n];
        }
    }
    __syncthreads();
    if (tid < NHEADS) {
        float bv = redVal[0][tid];
        int bs = redS[0][tid];
        for (int w = 1; w < 4; ++w) {
            float vv = redVal[w][tid];
            int ss = redS[w][tid];
            if (vv > bv || (vv == bv && ss < bs)) { bv = vv; bs = ss; }
        }
        sstar[tid] = bs;
    }
    __syncthreads();
    // gather: out[b,n,:] = x[b, sstar[n], :]
    #pragma unroll
    for (int n = 0; n < NHEADS; ++n) {
        const float4* src = (const float4*)(x + ((size_t)b * Sn + sstar[n]) * Hn);
        float4* dst = (float4*)(out + ((size_t)b * NHEADS + n) * Hn);
        dst[tid] = src[tid];
    }
}

// ----------------------------------------------------------------
extern "C" void kernel_launch(void* const* d_in, const int* in_sizes, int n_in,
                              void* d_out, int out_size, void* d_ws, size_t ws_size,
                              hipStream_t stream) {
    const float* x  = (const float*)d_in[0];
    const float* Wq = (const float*)d_in[1];
    const float* Wk = (const float*)d_in[2];
    const float* gu = (const float*)d_in[3];
    float* out = (float*)d_out;
    float* ws = (float*)d_ws;

    float* pe    = ws;                          // S*H   = 102400
    float* pesum = pe + (size_t)Sn * Hn;        // H     = 1024
    float* xsum  = pesum + Hn;                  // B*H   = 1048576
    float* ksum  = xsum + (size_t)Bn * Hn;      // B*J   = 524288
    float* kpart = ksum + (size_t)Bn * Jn;      // 8*B*J = 4194304
    float* v     = out;                         // B*N*H — reuse d_out as scratch for v

    k0a_pe   <<<dim3(Sn), dim3(256), 0, stream>>>(pe);
    k0b_pesum<<<dim3(Hn / 256), dim3(256), 0, stream>>>(pe, pesum);
    k1_xsum  <<<dim3(Bn), dim3(256), 0, stream>>>(x, pesum, xsum);
    k2p_gemm <<<dim3(Bn / 128, Jn / 128, KSPLIT), dim3(256), 0, stream>>>(xsum, Wk, kpart);
    k2r_reduce<<<dim3(Bn * Jn / 4 / 256), dim3(256), 0, stream>>>(kpart, ksum);
    k3p_gemm <<<dim3(Bn / 128, Hn / 128, NHEADS), dim3(256), 0, stream>>>(ksum, Wq, v);
    k4_final <<<dim3(Bn), dim3(256), 0, stream>>>(x, pe, v, gu, out);
}